// Round 5
// baseline (140.279 us; speedup 1.0000x reference)
//
#include <hip/hip_runtime.h>
#include <math.h>

// ---------------------------------------------------------------------------
// Barrier_Net, full-f16 MFMA (16x16x32), SINGLE-WAVE-PER-GROUP pipeline.
// R17 changes vs R16 (137.4 us, bn_main ~34 us): ALGEBRAIC STAGE FUSION.
// No nonlinearity between (Wp2,Wr1) and between (Wr2,Wpsi1), so prep
// pre-composes:
//   FN/FO : 0.5*(Wp2@Wr1)  (64x64), bias_f = 16|8 * bp2@Wr1 + br1 (f32 in ws)
//           -> G2N+RNA / G2O+ROA become ONE K=64 MFMA pass each; PHI gone.
//   ZN/ZO : Wr2n@Wpsi1[0:16], Wr2o@Wpsi1[16:32] (64x64 each)
//   WG    : Wpsi1[32:36] K=4 + combined bias row at k=4
//           (br2n@Wpsi1[0:16]+br2o@Wpsi1[16:32]+bpsi1), A has 1.0 at k=4
//           -> RNB+ROB+CAT+PSI1 become ONE 5-deep C-chained MFMA pass; CAT,
//           g-staging, CAT/PHI pads all gone.
// Pipeline/wave: stage NBA,OBA + barrier -> S1N->BIG -> S1O->BIG2 ->
//   FN(BIG in-place) -> FO(BIG2 in-place) -> PSI(gA,BIG,BIG2 -> h3 in BIG)
//   -> PSI2 -> epilogue.  3 LDS round-trips (was 5), ~100 fewer VALU/wave.
// R16 relu identity kept: Sum relu(x) = (Sum x + Sum|x|)/2, accS C-chained,
// accA += fabsf (1 VALU/elem); the /2 folded into FN/FO weights.
// A-frag: A[m=lane&15][k=(lane>>4)*8+j]; B-frag: B[k=(lane>>4)*8+j][n=lane&15]
// C/D: col=lane&15, row=(lane>>4)*4+reg.  (HW-verified R7..R12)
// In-place BIG overwrites are safe: every store transitively depends on the
// A-frag loads (per-wave DS is in-order, lds_order pins compiler order).
// nb = 131072 = 64*2048 -> 2048 full blocks, no partial groups.
// ---------------------------------------------------------------------------

typedef __attribute__((ext_vector_type(8))) _Float16 f16x8;
typedef __attribute__((ext_vector_type(2))) __fp16 fp16x2;
typedef __attribute__((ext_vector_type(4))) float f32x4;

#define XW 85     // floats per input row

// ---- B-frag table in d_ws: 46 frags x 64 lanes x 8 f16 + 128 f32 biases ----
#define FR_S1N  0    // 4: Wp1n K=4, bias bp1n @k4
#define FR_S1O  4    // 4: Wp1o K=2, bias bp1o @k2
#define FR_FN   8    // 8: 0.5*Wp2n@Wr1n  (kk*4+nt)
#define FR_FO   16   // 8: 0.5*Wp2o@Wr1o
#define FR_ZN   24   // 8: Wr2n@Wpsi1[0:16]
#define FR_ZO   32   // 8: Wr2o@Wpsi1[16:32]
#define FR_WG   40   // 4: Wpsi1[32:36] K=4, combined PSI1 bias @k4
#define FR_PSI2 44   // 2: Wpsi2 K=64 N=2
#define N_FRAGS 46
// f32 bias area at byte offset 46*1024: [0..63]=bias_fn, [64..127]=bias_fo

// ---- per-GROUP LDS layout (bytes); 4 groups (waves) per 256-thread block ----
#define BIG_STR 144
#define L_BIG  0        // 2304  NBA staging / h1n / z_n / h3
#define L_BIG2 2304     // 2304  h1o / z_o
#define L_OUT  4608     // 128
#define L_BAR  4736     // 128
#define L_OBA  4864     // 544 = 8 obst tiles x 68 B
#define GRP_LDS 5440    // x4 groups = 21760 B/block
#define NBA_STR 136     // staging tile stride inside BIG region
#define OBA_STR 68

#define H16_ONE 0x00003C00u   // f16 1.0 in low half of a dword

__device__ __forceinline__ float fast_rcp(float x)  { return __builtin_amdgcn_rcpf(x); }
__device__ __forceinline__ float fast_sqrt(float x) { return __builtin_amdgcn_sqrtf(x); }

__device__ __forceinline__ float two_tanh(float a) {
    float ax = fabsf(a);
    float e = __expf(2.0f * ax);
    float t = 1.0f - 2.0f * fast_rcp(e + 1.0f);
    return copysignf(2.0f * t, a);
}

// Compiler-only ordering barrier for wave-private LDS (R11-proven safe).
__device__ __forceinline__ void lds_order() {
    __asm__ __volatile__("" ::: "memory");
}

__device__ __forceinline__ unsigned pk2(float a, float b) {
    union { fp16x2 h; unsigned u; } t;
    t.h = __builtin_amdgcn_cvt_pkrtz(a, b);
    return t.u;
}
__device__ __forceinline__ f16x8 lds_af(const char* area, int stride, int off, int lane) {
    int mm = lane & 15, qq = lane >> 4;
    return *(const f16x8*)(area + mm * stride + off + qq * 16);
}
__device__ __forceinline__ f16x8 load_bh(const _Float16* wsf, int frag, int lane) {
    return ((const f16x8*)(wsf + (size_t)frag * 512))[lane];
}
__device__ __forceinline__ f32x4 cinit(float b) {
    f32x4 c; c[0] = b; c[1] = b; c[2] = b; c[3] = b; return c;
}
__device__ __forceinline__ f32x4 mfma1(f16x8 a, f16x8 b, f32x4 c) {
    return __builtin_amdgcn_mfma_f32_16x16x32_f16(a, b, c, 0, 0, 0);
}

// ---------------------------------------------------------------------------
// prep: pack (pre-composed) weights into f16 B-frag blocks.
// ---------------------------------------------------------------------------
__global__ void bn_prep(const float* __restrict__ Wp1n, const float* __restrict__ Wp2n,
                        const float* __restrict__ Wr1n, const float* __restrict__ Wr2n,
                        const float* __restrict__ Wp1o, const float* __restrict__ Wp2o,
                        const float* __restrict__ Wr1o, const float* __restrict__ Wr2o,
                        const float* __restrict__ Wpsi1, const float* __restrict__ Wpsi2,
                        const float* __restrict__ bp1n, const float* __restrict__ bp1o,
                        const float* __restrict__ bp2n, const float* __restrict__ bp2o,
                        const float* __restrict__ br1n, const float* __restrict__ br1o,
                        const float* __restrict__ br2n, const float* __restrict__ br2o,
                        const float* __restrict__ bpsi1,
                        _Float16* __restrict__ wsf)
{
    int f = blockIdx.x;
    int lane = threadIdx.x;   // 64
    int q = lane >> 4, c = lane & 15;

    if (f >= N_FRAGS) {
        // f==46: bias_fn = 16*bp2n@Wr1n + br1n ; f==47: bias_fo = 8*bp2o@Wr1o + br1o
        float* dst = (float*)(wsf + (size_t)N_FRAGS * 512) + (f - N_FRAGS) * 64;
        if (lane < 64) {
            float s = 0.f;
            if (f == N_FRAGS) {
                for (int e = 0; e < 16; ++e) s = fmaf(bp2n[e], Wr1n[e * 64 + lane], s);
                dst[lane] = 16.f * s + br1n[lane];
            } else {
                for (int e = 0; e < 16; ++e) s = fmaf(bp2o[e], Wr1o[e * 64 + lane], s);
                dst[lane] = 8.f * s + br1o[lane];
            }
        }
        return;
    }

    _Float16* dstf = wsf + (size_t)f * 512 + lane * 8;

    if (f < 8) {
        // S1N (0..3): Wp1n (4,64), bias @k=4.  S1O (4..7): Wp1o (2,64), bias @k=2.
        const float* W   = (f < 4) ? Wp1n : Wp1o;
        const float* bia = (f < 4) ? bp1n : bp1o;
        int K  = (f < 4) ? 4 : 2;
        int nt = f & 3;
        for (int j = 0; j < 8; ++j) {
            int k = q * 8 + j;
            int n = nt * 16 + c;
            float v = 0.f;
            if (k < K) v = W[k * 64 + n];
            else if (k == K) v = bia[n];
            dstf[j] = (_Float16)v;
        }
    } else if (f < 24) {
        // FN (8..15) / FO (16..23): 0.5 * Wp2 (64,16) @ Wr1 (16,64)
        int rel = (f - 8) & 7;
        bool isN = f < 16;
        const float* Wa = isN ? Wp2n : Wp2o;
        const float* Wb = isN ? Wr1n : Wr1o;
        int kk = rel >> 2, nt = rel & 3;
        for (int j = 0; j < 8; ++j) {
            int k = kk * 32 + q * 8 + j;
            int n = nt * 16 + c;
            float s = 0.f;
            for (int e = 0; e < 16; ++e) s = fmaf(Wa[k * 16 + e], Wb[e * 64 + n], s);
            dstf[j] = (_Float16)(0.5f * s);
        }
    } else if (f < 40) {
        // ZN (24..31): Wr2n(64,16)@Wpsi1[0:16,:]  ZO (32..39): Wr2o@Wpsi1[16:32,:]
        int rel = (f - 24) & 7;
        bool isN = f < 32;
        const float* Wa = isN ? Wr2n : Wr2o;
        int roff = isN ? 0 : 16;
        int kk = rel >> 2, nt = rel & 3;
        for (int j = 0; j < 8; ++j) {
            int k = kk * 32 + q * 8 + j;
            int n = nt * 16 + c;
            float s = 0.f;
            for (int e = 0; e < 16; ++e) s = fmaf(Wa[k * 16 + e], Wpsi1[(roff + e) * 64 + n], s);
            dstf[j] = (_Float16)s;
        }
    } else if (f < 44) {
        // WG (40..43): K=4 rows Wpsi1[32..35]; k==4 -> combined PSI1 bias
        int nt = f - 40;
        for (int j = 0; j < 8; ++j) {
            int k = q * 8 + j;
            int n = nt * 16 + c;
            float v = 0.f;
            if (k < 4) v = Wpsi1[(32 + k) * 64 + n];
            else if (k == 4) {
                float s = bpsi1[n];
                for (int e = 0; e < 16; ++e) {
                    s = fmaf(br2n[e], Wpsi1[e * 64 + n], s);
                    s = fmaf(br2o[e], Wpsi1[(16 + e) * 64 + n], s);
                }
                v = s;
            }
            dstf[j] = (_Float16)v;
        }
    } else {
        // PSI2 (44..45): Wpsi2 (64,2)
        int kk = f - 44;
        for (int j = 0; j < 8; ++j) {
            int k = kk * 32 + q * 8 + j;
            float v = (c < 2) ? Wpsi2[k * 2 + c] : 0.f;
            dstf[j] = (_Float16)v;
        }
    }
}

// ---------------------------------------------------------------------------
// main: 1 wave per 16-row group; block 256 = 4 independent waves/groups.
// ---------------------------------------------------------------------------
__global__ __launch_bounds__(256, 5) void bn_main(
    const float* __restrict__ x, const _Float16* __restrict__ wsf,
    const float* __restrict__ bpsi2,
    float* __restrict__ out, int nb)
{
    __shared__ char smem[4 * GRP_LDS];
    const int lane = threadIdx.x & 63;
    const int wid  = threadIdx.x >> 6;            // 0..3 = group within block
    const int group = blockIdx.x * 4 + wid;
    const int row0 = group * 16;                  // nb is exact multiple of 64

    char* Gl   = smem + wid * GRP_LDS;
    char* BIG  = Gl + L_BIG;
    char* BIG2 = Gl + L_BIG2;
    char* OUTA = Gl + L_OUT;
    char* BAR  = Gl + L_BAR;
    char* OBA  = Gl + L_OBA;
    char* NBA  = BIG;                  // staging aliases BIG

    const int m = lane & 15, q = lane >> 4, c = m;
    const float* xg   = x + (size_t)row0 * XW;    // group base
    const float* xrow = xg + (size_t)m * XW;      // this lane's batch row

    const float* BFN = (const float*)(wsf + (size_t)N_FRAGS * 512);      // bias_fn
    const float* BFO = BFN + 64;                                         // bias_fo

    const f32x4 ZC = cinit(0.f);       // shared zero C-operand (invariant)

    // ---- stage neighbor features -> NBA (= BIG) as packed f16 A-tiles ----
    {
        int ln5 = lane >> 5;                 // 0/1
        int pr  = lane & 31;
        int mm0 = pr >> 1, fp = pr & 1;
        char* db = NBA + mm0 * NBA_STR + fp * 4;
        const float* s0 = xg + (size_t)ln5 * XW + 5 + pr * 2;
        #pragma unroll
        for (int t = 0; t < 8; ++t) {
            const float* s = s0 + (size_t)(2 * t) * XW;
            *(unsigned*)(db + (2 * t + ln5) * 8) = pk2(s[0], s[1]);
        }
    }
    // ---- stage obstacle features -> OBA (separate region) ----
    {
        int r8 = lane >> 3;                  // 0..7
        int oo = lane & 7;
        char* db = OBA + oo * OBA_STR;
        const float* s0 = xg + (size_t)r8 * XW + 69 + oo * 2;
        #pragma unroll
        for (int t = 0; t < 2; ++t) {
            const float* s = s0 + (size_t)(8 * t) * XW;
            *(unsigned*)(db + (8 * t + r8) * 4) = pk2(s[0], s[1]);
        }
    }

    // ---- barrier terms: lane (row m, quad q): nbrs 4q..4q+3, obs 2q..2q+1 ----
    {
        float bx = 0.f, by = 0.f;
        #pragma unroll
        for (int i = 0; i < 4; ++i) {
            int n = 4 * q + i;
            float px = -xrow[5 + 4 * n], py = -xrow[6 + 4 * n];
            float nrm = fast_sqrt(px * px + py * py);
            float coef = 0.05f * fast_rcp(nrm * (nrm - 0.3f));
            bx = fmaf(coef, px, bx);
            by = fmaf(coef, py, by);
        }
        #pragma unroll
        for (int i = 0; i < 2; ++i) {
            int o = 2 * q + i;
            float px = -xrow[69 + 2 * o], py = -xrow[70 + 2 * o];
            float nrm = fast_sqrt(px * px + py * py);
            float coef = 0.05f * fast_rcp(nrm * (nrm - 0.3f));
            bx = fmaf(coef, px, bx);
            by = fmaf(coef, py, by);
        }
        bx += __shfl_xor(bx, 16); by += __shfl_xor(by, 16);
        bx += __shfl_xor(bx, 32); by += __shfl_xor(by, 32);
        if (q == 0) { float2 bb; bb.x = bx; bb.y = by; *(float2*)(BAR + m * 8) = bb; }
    }
    lds_order();

    // ========== S1N: Sum relu via (Sum x + Sum |x|); store 2*h1n -> BIG ====
    {
        f16x8 Bs1n[4];
        #pragma unroll
        for (int nt = 0; nt < 4; ++nt) Bs1n[nt] = load_bh(wsf, FR_S1N + nt, lane);

        const int m8 = m * 8;
        f32x4 accS[4], accA[4];
        #pragma unroll
        for (int nt = 0; nt < 4; ++nt) { accS[nt] = cinit(0.f); accA[nt] = cinit(0.f); }
        union { f16x8 v; unsigned u[4]; uint2 h[2]; } A;
        A.u[2] = H16_ONE; A.u[3] = 0;        // k=4 bias slot
        #pragma unroll
        for (int mm = 0; mm < 16; ++mm) {
            A.h[0] = *(const uint2*)(NBA + mm * NBA_STR + m8);
            #pragma unroll
            for (int nt = 0; nt < 4; ++nt) {
                accS[nt] = mfma1(A.v, Bs1n[nt], accS[nt]);   // Sum x (free)
                f32x4 cc = mfma1(A.v, Bs1n[nt], ZC);         // per-term x
                #pragma unroll
                for (int reg = 0; reg < 4; ++reg)
                    accA[nt][reg] += fabsf(cc[reg]);         // Sum |x|, 1 VALU
            }
        }
        lds_order();   // NBA reads done; BIG stores below alias it
        #pragma unroll
        for (int nt = 0; nt < 4; ++nt)
            #pragma unroll
            for (int reg = 0; reg < 4; ++reg)
                *(_Float16*)(BIG + (q * 4 + reg) * BIG_STR + (nt * 16 + c) * 2)
                    = (_Float16)(accS[nt][reg] + accA[nt][reg]);
    }
    lds_order();

    // ========== S1O: same, 8 obstacles; store 2*h1o -> BIG2 ================
    {
        f16x8 Bs1o[4];
        #pragma unroll
        for (int nt = 0; nt < 4; ++nt) Bs1o[nt] = load_bh(wsf, FR_S1O + nt, lane);

        const int m4 = m * 4;
        f32x4 accS[4], accA[4];
        #pragma unroll
        for (int nt = 0; nt < 4; ++nt) { accS[nt] = cinit(0.f); accA[nt] = cinit(0.f); }
        union { f16x8 v; unsigned u[4]; } A;
        A.u[1] = H16_ONE; A.u[2] = 0; A.u[3] = 0;   // k=2 bias slot
        #pragma unroll
        for (int oo = 0; oo < 8; ++oo) {
            A.u[0] = *(const unsigned*)(OBA + oo * OBA_STR + m4);
            #pragma unroll
            for (int nt = 0; nt < 4; ++nt) {
                accS[nt] = mfma1(A.v, Bs1o[nt], accS[nt]);
                f32x4 cc = mfma1(A.v, Bs1o[nt], ZC);
                #pragma unroll
                for (int reg = 0; reg < 4; ++reg)
                    accA[nt][reg] += fabsf(cc[reg]);
            }
        }
        #pragma unroll
        for (int nt = 0; nt < 4; ++nt)
            #pragma unroll
            for (int reg = 0; reg < 4; ++reg)
                *(_Float16*)(BIG2 + (q * 4 + reg) * BIG_STR + (nt * 16 + c) * 2)
                    = (_Float16)(accS[nt][reg] + accA[nt][reg]);
    }
    lds_order();

    // ========== FN: z_n = relu(2h1n @ 0.5*Wp2n@Wr1n + bias_fn) (in-place) ==
    {
        f16x8 A0 = lds_af(BIG, BIG_STR, 0, lane);
        f16x8 A1 = lds_af(BIG, BIG_STR, 64, lane);
        lds_order();
        #pragma unroll
        for (int nt = 0; nt < 4; ++nt) {
            f16x8 B0 = load_bh(wsf, FR_FN + nt, lane);
            f16x8 B1 = load_bh(wsf, FR_FN + 4 + nt, lane);
            f32x4 cc = mfma1(A0, B0, cinit(BFN[nt * 16 + c]));
            cc = mfma1(A1, B1, cc);
            #pragma unroll
            for (int reg = 0; reg < 4; ++reg)
                *(_Float16*)(BIG + (q * 4 + reg) * BIG_STR + (nt * 16 + c) * 2)
                    = (_Float16)fmaxf(cc[reg], 0.f);
        }
    }
    lds_order();

    // ========== FO: z_o = relu(2h1o @ 0.5*Wp2o@Wr1o + bias_fo) (in-place) ==
    {
        f16x8 A0 = lds_af(BIG2, BIG_STR, 0, lane);
        f16x8 A1 = lds_af(BIG2, BIG_STR, 64, lane);
        lds_order();
        #pragma unroll
        for (int nt = 0; nt < 4; ++nt) {
            f16x8 B0 = load_bh(wsf, FR_FO + nt, lane);
            f16x8 B1 = load_bh(wsf, FR_FO + 4 + nt, lane);
            f32x4 cc = mfma1(A0, B0, cinit(BFO[nt * 16 + c]));
            cc = mfma1(A1, B1, cc);
            #pragma unroll
            for (int reg = 0; reg < 4; ++reg)
                *(_Float16*)(BIG2 + (q * 4 + reg) * BIG_STR + (nt * 16 + c) * 2)
                    = (_Float16)fmaxf(cc[reg], 0.f);
        }
    }
    lds_order();

    // ========== PSI: h3 = relu(g@WG + z_n@ZN + z_o@ZO) (bias in WG k=4) ====
    {
        union { f16x8 v; unsigned u[4]; } gA;
        gA.u[0] = pk2(xrow[1], xrow[2]);
        gA.u[1] = pk2(xrow[3], xrow[4]);
        gA.u[2] = H16_ONE;                  // k=4 bias slot
        gA.u[3] = 0;

        f16x8 An0 = lds_af(BIG,  BIG_STR, 0, lane);
        f16x8 An1 = lds_af(BIG,  BIG_STR, 64, lane);
        f16x8 Ao0 = lds_af(BIG2, BIG_STR, 0, lane);
        f16x8 Ao1 = lds_af(BIG2, BIG_STR, 64, lane);
        lds_order();
        #pragma unroll
        for (int nt = 0; nt < 4; ++nt) {
            f16x8 Bg  = load_bh(wsf, FR_WG + nt, lane);
            f16x8 Bn0 = load_bh(wsf, FR_ZN + nt, lane);
            f16x8 Bn1 = load_bh(wsf, FR_ZN + 4 + nt, lane);
            f16x8 Bo0 = load_bh(wsf, FR_ZO + nt, lane);
            f16x8 Bo1 = load_bh(wsf, FR_ZO + 4 + nt, lane);
            f32x4 cc = mfma1(gA.v, Bg, ZC);
            cc = mfma1(An0, Bn0, cc);
            cc = mfma1(An1, Bn1, cc);
            cc = mfma1(Ao0, Bo0, cc);
            cc = mfma1(Ao1, Bo1, cc);
            #pragma unroll
            for (int reg = 0; reg < 4; ++reg)
                *(_Float16*)(BIG + (q * 4 + reg) * BIG_STR + (nt * 16 + c) * 2)
                    = (_Float16)fmaxf(cc[reg], 0.f);
        }
    }
    lds_order();

    // ========== PSI2 -> OUT ================================================
    {
        float b_p2 = (c < 2) ? bpsi2[c] : 0.f;
        f16x8 Bp20 = load_bh(wsf, FR_PSI2 + 0, lane);
        f16x8 Bp21 = load_bh(wsf, FR_PSI2 + 1, lane);
        f16x8 A0 = lds_af(BIG, BIG_STR, 0, lane);
        f16x8 A1 = lds_af(BIG, BIG_STR, 64, lane);
        f32x4 ca = mfma1(A0, Bp20, cinit(b_p2));
        f32x4 cb = mfma1(A1, Bp21, ZC);
        if (c < 2) {
            #pragma unroll
            for (int reg = 0; reg < 4; ++reg)
                *(float*)(OUTA + (q * 4 + reg) * 8 + c * 4) = ca[reg] + cb[reg];
        }
    }
    lds_order();

    // epilogue
    if (lane < 16) {
        float2 a  = *(const float2*)(OUTA + lane * 8);
        float2 bb = *(const float2*)(BAR + lane * 8);
        float a0 = two_tanh(a.x) + bb.x;
        float a1 = two_tanh(a.y) + bb.y;
        float amax = fmaxf(fabsf(a0), fabsf(a1));
        float inv_alpha = fmaxf(amax * 0.5f, 1.0f);
        float rr = fast_rcp(inv_alpha);
        float2 o; o.x = a0 * rr; o.y = a1 * rr;
        *(float2*)(out + (size_t)(row0 + lane) * 2) = o;
    }
}

extern "C" void kernel_launch(void* const* d_in, const int* in_sizes, int n_in,
                              void* d_out, int out_size, void* d_ws, size_t ws_size,
                              hipStream_t stream) {
    const float* x     = (const float*)d_in[0];
    const float* Wp1n  = (const float*)d_in[1];
    const float* bp1n  = (const float*)d_in[2];
    const float* Wp2n  = (const float*)d_in[3];
    const float* bp2n  = (const float*)d_in[4];
    const float* Wr1n  = (const float*)d_in[5];
    const float* br1n  = (const float*)d_in[6];
    const float* Wr2n  = (const float*)d_in[7];
    const float* br2n  = (const float*)d_in[8];
    const float* Wp1o  = (const float*)d_in[9];
    const float* bp1o  = (const float*)d_in[10];
    const float* Wp2o  = (const float*)d_in[11];
    const float* bp2o  = (const float*)d_in[12];
    const float* Wr1o  = (const float*)d_in[13];
    const float* br1o  = (const float*)d_in[14];
    const float* Wr2o  = (const float*)d_in[15];
    const float* br2o  = (const float*)d_in[16];
    const float* Wpsi1 = (const float*)d_in[17];
    const float* bpsi1 = (const float*)d_in[18];
    const float* Wpsi2 = (const float*)d_in[19];
    const float* bpsi2 = (const float*)d_in[20];
    float* out = (float*)d_out;

    int nb = in_sizes[0] / XW;               // 131072
    _Float16* wsf = (_Float16*)d_ws;         // ~47.6 KB frag+bias table

    bn_prep<<<N_FRAGS + 2, 64, 0, stream>>>(Wp1n, Wp2n, Wr1n, Wr2n,
                                            Wp1o, Wp2o, Wr1o, Wr2o,
                                            Wpsi1, Wpsi2,
                                            bp1n, bp1o, bp2n, bp2o,
                                            br1n, br1o, br2n, br2o,
                                            bpsi1, wsf);

    int groups = (nb + 15) / 16;             // 8192
    int blocks = (groups + 3) / 4;           // 2048 (4 groups per block)
    bn_main<<<blocks, 256, 0, stream>>>(x, wsf, bpsi2, out, nb);
}

// Round 6
// 138.074 us; speedup vs baseline: 1.0160x; 1.0160x over previous
//
#include <hip/hip_runtime.h>
#include <math.h>

// ---------------------------------------------------------------------------
// Barrier_Net, full-f16 MFMA (16x16x32), SINGLE-WAVE-PER-GROUP pipeline.
// R18 changes vs R17 (140.3 us): ILP RESTRUCTURE + PACKED-SUM.
//   * Obstacles live in REGISTERS (8 packed dwords from xrow[69..84]); the
//     whole S1O stage (packed-S + per-term |x|) is register-only and runs
//     BETWEEN the NBA staging stores and S1N's first NBA read -> hides
//     staging latency with real work; OBA LDS staging deleted.
//   * Packed-SUM: Sum_m x_m via K-packed MFMAs instead of 16-deep C-chains:
//       S1N: A[m][k]=e[k>>2][k&3], B[k][n]=Wp1n[k&3][n] (same B both halves)
//            -> 2 chained MFMAs/nt.  S1O: 1 MFMA/nt (16 k-slots used).
//       Bias enters via f32 C-init (16*bp1n / 8*bp1o precomputed in ws).
//     MFMA/wave 230 -> 146.  |x| path unchanged (1 VALU/elem floor).
//   * lds_order() fences cut 8 -> 4 (they block ALL compiler reordering);
//     FN+FO merged into one region (A-frags upfront, 8 independent blocks);
//     gA built at wave start. In-wave DS is HW-in-order; same-object alias
//     analysis preserves read->write order (R11/R17-proven).
// R17 fusion kept: FN/FO = 0.5*(Wp2@Wr1), ZN/ZO = Wr2@Wpsi1 splits, WG with
// combined bias row; R16 relu identity kept.
// A-frag: A[m=lane&15][k=(lane>>4)*8+j]; B-frag: B[k=(lane>>4)*8+j][n=lane&15]
// C/D: col=lane&15, row=(lane>>4)*4+reg.  (HW-verified R7..R12)
// nb = 131072 = 64*2048 -> 2048 full blocks, no partial groups.
// ---------------------------------------------------------------------------

typedef __attribute__((ext_vector_type(8))) _Float16 f16x8;
typedef __attribute__((ext_vector_type(2))) __fp16 fp16x2;
typedef __attribute__((ext_vector_type(4))) float f32x4;

#define XW 85     // floats per input row

// ---- B-frag table in d_ws: 54 frags x 64 lanes x 8 f16 + 256 f32 biases ----
#define FR_S1N  0    // 4: Wp1n K=4, bias bp1n @k4
#define FR_S1O  4    // 4: Wp1o K=2, bias bp1o @k2
#define FR_FN   8    // 8: 0.5*Wp2n@Wr1n  (kk*4+nt)
#define FR_FO   16   // 8: 0.5*Wp2o@Wr1o
#define FR_ZN   24   // 8: Wr2n@Wpsi1[0:16]
#define FR_ZO   32   // 8: Wr2o@Wpsi1[16:32]
#define FR_WG   40   // 4: Wpsi1[32:36] K=4, combined PSI1 bias @k4
#define FR_PSI2 44   // 2: Wpsi2 K=64 N=2
#define FR_SPN  46   // 4: packed-sum B for S1N: B[k][n]=Wp1n[k&3][n]
#define FR_SPO  50   // 4: packed-sum B for S1O: k<16 ? Wp1o[k&1][n] : 0
#define N_FRAGS 54
// f32 bias area at 54*512 f16: [0..63]=bias_fn, [64..127]=bias_fo,
//                              [128..191]=16*bp1n, [192..255]=8*bp1o

// ---- per-GROUP LDS layout (bytes); 4 groups (waves) per 256-thread block ----
#define BIG_STR 144
#define L_BIG  0        // 2304  NBA staging / h1n / z_n / h3
#define L_BIG2 2304     // 2304  h1o / z_o
#define L_OUT  4608     // 128
#define L_BAR  4736     // 128
#define GRP_LDS 4864    // x4 groups = 19456 B/block
#define NBA_STR 136     // staging tile stride inside BIG region

#define H16_ONE 0x00003C00u   // f16 1.0 in low half of a dword

__device__ __forceinline__ float fast_rcp(float x)  { return __builtin_amdgcn_rcpf(x); }
__device__ __forceinline__ float fast_sqrt(float x) { return __builtin_amdgcn_sqrtf(x); }

__device__ __forceinline__ float two_tanh(float a) {
    float ax = fabsf(a);
    float e = __expf(2.0f * ax);
    float t = 1.0f - 2.0f * fast_rcp(e + 1.0f);
    return copysignf(2.0f * t, a);
}

// Compiler-only ordering barrier for wave-private LDS (R11-proven safe).
__device__ __forceinline__ void lds_order() {
    __asm__ __volatile__("" ::: "memory");
}

__device__ __forceinline__ unsigned pk2(float a, float b) {
    union { fp16x2 h; unsigned u; } t;
    t.h = __builtin_amdgcn_cvt_pkrtz(a, b);
    return t.u;
}
__device__ __forceinline__ f16x8 lds_af(const char* area, int stride, int off, int lane) {
    int mm = lane & 15, qq = lane >> 4;
    return *(const f16x8*)(area + mm * stride + off + qq * 16);
}
__device__ __forceinline__ f16x8 load_bh(const _Float16* wsf, int frag, int lane) {
    return ((const f16x8*)(wsf + (size_t)frag * 512))[lane];
}
__device__ __forceinline__ f32x4 cinit(float b) {
    f32x4 c; c[0] = b; c[1] = b; c[2] = b; c[3] = b; return c;
}
__device__ __forceinline__ f32x4 mfma1(f16x8 a, f16x8 b, f32x4 c) {
    return __builtin_amdgcn_mfma_f32_16x16x32_f16(a, b, c, 0, 0, 0);
}

// ---------------------------------------------------------------------------
// prep: pack (pre-composed) weights into f16 B-frag blocks + f32 bias rows.
// ---------------------------------------------------------------------------
__global__ void bn_prep(const float* __restrict__ Wp1n, const float* __restrict__ Wp2n,
                        const float* __restrict__ Wr1n, const float* __restrict__ Wr2n,
                        const float* __restrict__ Wp1o, const float* __restrict__ Wp2o,
                        const float* __restrict__ Wr1o, const float* __restrict__ Wr2o,
                        const float* __restrict__ Wpsi1, const float* __restrict__ Wpsi2,
                        const float* __restrict__ bp1n, const float* __restrict__ bp1o,
                        const float* __restrict__ bp2n, const float* __restrict__ bp2o,
                        const float* __restrict__ br1n, const float* __restrict__ br1o,
                        const float* __restrict__ br2n, const float* __restrict__ br2o,
                        const float* __restrict__ bpsi1,
                        _Float16* __restrict__ wsf)
{
    int f = blockIdx.x;
    int lane = threadIdx.x;   // 64
    int q = lane >> 4, c = lane & 15;

    if (f >= N_FRAGS) {
        // f 54: bias_fn = 16*bp2n@Wr1n + br1n ; 55: bias_fo = 8*bp2o@Wr1o + br1o
        // f 56: 16*bp1n ; 57: 8*bp1o
        float* dst = (float*)(wsf + (size_t)N_FRAGS * 512) + (f - N_FRAGS) * 64;
        if (lane < 64) {
            if (f == N_FRAGS) {
                float s = 0.f;
                for (int e = 0; e < 16; ++e) s = fmaf(bp2n[e], Wr1n[e * 64 + lane], s);
                dst[lane] = 16.f * s + br1n[lane];
            } else if (f == N_FRAGS + 1) {
                float s = 0.f;
                for (int e = 0; e < 16; ++e) s = fmaf(bp2o[e], Wr1o[e * 64 + lane], s);
                dst[lane] = 8.f * s + br1o[lane];
            } else if (f == N_FRAGS + 2) {
                dst[lane] = 16.f * bp1n[lane];
            } else {
                dst[lane] = 8.f * bp1o[lane];
            }
        }
        return;
    }

    _Float16* dstf = wsf + (size_t)f * 512 + lane * 8;

    if (f < 8) {
        // S1N (0..3): Wp1n (4,64), bias @k=4.  S1O (4..7): Wp1o (2,64), bias @k=2.
        const float* W   = (f < 4) ? Wp1n : Wp1o;
        const float* bia = (f < 4) ? bp1n : bp1o;
        int K  = (f < 4) ? 4 : 2;
        int nt = f & 3;
        for (int j = 0; j < 8; ++j) {
            int k = q * 8 + j;
            int n = nt * 16 + c;
            float v = 0.f;
            if (k < K) v = W[k * 64 + n];
            else if (k == K) v = bia[n];
            dstf[j] = (_Float16)v;
        }
    } else if (f < 24) {
        // FN (8..15) / FO (16..23): 0.5 * Wp2 (64,16) @ Wr1 (16,64)
        int rel = (f - 8) & 7;
        bool isN = f < 16;
        const float* Wa = isN ? Wp2n : Wp2o;
        const float* Wb = isN ? Wr1n : Wr1o;
        int kk = rel >> 2, nt = rel & 3;
        for (int j = 0; j < 8; ++j) {
            int k = kk * 32 + q * 8 + j;
            int n = nt * 16 + c;
            float s = 0.f;
            for (int e = 0; e < 16; ++e) s = fmaf(Wa[k * 16 + e], Wb[e * 64 + n], s);
            dstf[j] = (_Float16)(0.5f * s);
        }
    } else if (f < 40) {
        // ZN (24..31): Wr2n(64,16)@Wpsi1[0:16,:]  ZO (32..39): Wr2o@Wpsi1[16:32,:]
        int rel = (f - 24) & 7;
        bool isN = f < 32;
        const float* Wa = isN ? Wr2n : Wr2o;
        int roff = isN ? 0 : 16;
        int kk = rel >> 2, nt = rel & 3;
        for (int j = 0; j < 8; ++j) {
            int k = kk * 32 + q * 8 + j;
            int n = nt * 16 + c;
            float s = 0.f;
            for (int e = 0; e < 16; ++e) s = fmaf(Wa[k * 16 + e], Wpsi1[(roff + e) * 64 + n], s);
            dstf[j] = (_Float16)s;
        }
    } else if (f < 44) {
        // WG (40..43): K=4 rows Wpsi1[32..35]; k==4 -> combined PSI1 bias
        int nt = f - 40;
        for (int j = 0; j < 8; ++j) {
            int k = q * 8 + j;
            int n = nt * 16 + c;
            float v = 0.f;
            if (k < 4) v = Wpsi1[(32 + k) * 64 + n];
            else if (k == 4) {
                float s = bpsi1[n];
                for (int e = 0; e < 16; ++e) {
                    s = fmaf(br2n[e], Wpsi1[e * 64 + n], s);
                    s = fmaf(br2o[e], Wpsi1[(16 + e) * 64 + n], s);
                }
                v = s;
            }
            dstf[j] = (_Float16)v;
        }
    } else if (f < 46) {
        // PSI2 (44..45): Wpsi2 (64,2)
        int kk = f - 44;
        for (int j = 0; j < 8; ++j) {
            int k = kk * 32 + q * 8 + j;
            float v = (c < 2) ? Wpsi2[k * 2 + c] : 0.f;
            dstf[j] = (_Float16)v;
        }
    } else if (f < 50) {
        // SPN (46..49): packed-sum B: B[k][n] = Wp1n[k&3][n], all 32 k
        int nt = f - 46;
        for (int j = 0; j < 8; ++j) {
            int k = q * 8 + j;
            int n = nt * 16 + c;
            dstf[j] = (_Float16)Wp1n[(k & 3) * 64 + n];
        }
    } else {
        // SPO (50..53): packed-sum B: k<16 ? Wp1o[k&1][n] : 0
        int nt = f - 50;
        for (int j = 0; j < 8; ++j) {
            int k = q * 8 + j;
            int n = nt * 16 + c;
            float v = (k < 16) ? Wp1o[(k & 1) * 64 + n] : 0.f;
            dstf[j] = (_Float16)v;
        }
    }
}

// ---------------------------------------------------------------------------
// main: 1 wave per 16-row group; block 256 = 4 independent waves/groups.
// ---------------------------------------------------------------------------
__global__ __launch_bounds__(256, 5) void bn_main(
    const float* __restrict__ x, const _Float16* __restrict__ wsf,
    const float* __restrict__ bpsi2,
    float* __restrict__ out, int nb)
{
    __shared__ char smem[4 * GRP_LDS];
    const int lane = threadIdx.x & 63;
    const int wid  = threadIdx.x >> 6;            // 0..3 = group within block
    const int group = blockIdx.x * 4 + wid;
    const int row0 = group * 16;                  // nb is exact multiple of 64

    char* Gl   = smem + wid * GRP_LDS;
    char* BIG  = Gl + L_BIG;
    char* BIG2 = Gl + L_BIG2;
    char* OUTA = Gl + L_OUT;
    char* BAR  = Gl + L_BAR;
    char* NBA  = BIG;                  // staging aliases BIG

    const int m = lane & 15, q = lane >> 4, c = m;
    const float* xg   = x + (size_t)row0 * XW;    // group base
    const float* xrow = xg + (size_t)m * XW;      // this lane's batch row

    const float* BFN = (const float*)(wsf + (size_t)N_FRAGS * 512);  // bias_fn
    const float* BFO = BFN + 64;                                     // bias_fo
    const float* BSN = BFN + 128;                                    // 16*bp1n
    const float* BSO = BFN + 192;                                    // 8*bp1o

    const f32x4 ZC = cinit(0.f);       // shared zero C-operand (invariant)

    // ---- stage neighbor features -> NBA (= BIG) as packed f16 A-tiles ----
    {
        int ln5 = lane >> 5;                 // 0/1
        int pr  = lane & 31;
        int mm0 = pr >> 1, fp = pr & 1;
        char* db = NBA + mm0 * NBA_STR + fp * 4;
        const float* s0 = xg + (size_t)ln5 * XW + 5 + pr * 2;
        #pragma unroll
        for (int t = 0; t < 8; ++t) {
            const float* s = s0 + (size_t)(2 * t) * XW;
            *(unsigned*)(db + (2 * t + ln5) * 8) = pk2(s[0], s[1]);
        }
    }

    // ---- gA for PSI (register, built early) ----
    union { f16x8 v; unsigned u[4]; } gA;
    gA.u[0] = pk2(xrow[1], xrow[2]);
    gA.u[1] = pk2(xrow[3], xrow[4]);
    gA.u[2] = H16_ONE;                  // k=4 bias slot
    gA.u[3] = 0;

    // ---- obstacle features -> registers (packed f16 dwords) ----
    unsigned obs[8];
    #pragma unroll
    for (int t = 0; t < 8; ++t)
        obs[t] = pk2(xrow[69 + 2 * t], xrow[70 + 2 * t]);

    // ---- barrier terms: lane (row m, quad q): nbrs 4q..4q+3, obs 2q..2q+1 ----
    // (raw f32 global reads: f16 would lose precision near the nrm ~ D pole)
    {
        float bx = 0.f, by = 0.f;
        #pragma unroll
        for (int i = 0; i < 4; ++i) {
            int n = 4 * q + i;
            float px = -xrow[5 + 4 * n], py = -xrow[6 + 4 * n];
            float nrm = fast_sqrt(px * px + py * py);
            float coef = 0.05f * fast_rcp(nrm * (nrm - 0.3f));
            bx = fmaf(coef, px, bx);
            by = fmaf(coef, py, by);
        }
        #pragma unroll
        for (int i = 0; i < 2; ++i) {
            int o = 2 * q + i;
            float px = -xrow[69 + 2 * o], py = -xrow[70 + 2 * o];
            float nrm = fast_sqrt(px * px + py * py);
            float coef = 0.05f * fast_rcp(nrm * (nrm - 0.3f));
            bx = fmaf(coef, px, bx);
            by = fmaf(coef, py, by);
        }
        bx += __shfl_xor(bx, 16); by += __shfl_xor(by, 16);
        bx += __shfl_xor(bx, 32); by += __shfl_xor(by, 32);
        if (q == 0) { float2 bb; bb.x = bx; bb.y = by; *(float2*)(BAR + m * 8) = bb; }
    }

    // ========== S1O (REGISTER-ONLY; runs while NBA staging lands) ==========
    // packed-S: A[m][k] = obs feat (k<16: obst k>>1, feat k&1); 1 MFMA/nt.
    // per-term |x|: A word0 = obs[oo], bias 1.0 @k=2.
    {
        f16x8 Bspo[4], Bs1o[4];
        #pragma unroll
        for (int nt = 0; nt < 4; ++nt) {
            Bspo[nt] = load_bh(wsf, FR_SPO + nt, lane);
            Bs1o[nt] = load_bh(wsf, FR_S1O + nt, lane);
        }
        union { f16x8 v; unsigned u[4]; } Apo;
        Apo.u[0] = q == 0 ? obs[0] : (q == 1 ? obs[4] : 0u);
        Apo.u[1] = q == 0 ? obs[1] : (q == 1 ? obs[5] : 0u);
        Apo.u[2] = q == 0 ? obs[2] : (q == 1 ? obs[6] : 0u);
        Apo.u[3] = q == 0 ? obs[3] : (q == 1 ? obs[7] : 0u);

        f32x4 accS[4], accA[4];
        #pragma unroll
        for (int nt = 0; nt < 4; ++nt) {
            accS[nt] = mfma1(Apo.v, Bspo[nt], cinit(BSO[nt * 16 + c]));
            accA[nt] = cinit(0.f);
        }
        union { f16x8 v; unsigned u[4]; } A;
        A.u[1] = H16_ONE; A.u[2] = 0; A.u[3] = 0;   // k=2 bias slot
        #pragma unroll
        for (int oo = 0; oo < 8; ++oo) {
            A.u[0] = obs[oo];
            #pragma unroll
            for (int nt = 0; nt < 4; ++nt) {
                f32x4 cc = mfma1(A.v, Bs1o[nt], ZC);
                #pragma unroll
                for (int reg = 0; reg < 4; ++reg)
                    accA[nt][reg] += fabsf(cc[reg]);
            }
        }
        #pragma unroll
        for (int nt = 0; nt < 4; ++nt)
            #pragma unroll
            for (int reg = 0; reg < 4; ++reg)
                *(_Float16*)(BIG2 + (q * 4 + reg) * BIG_STR + (nt * 16 + c) * 2)
                    = (_Float16)(accS[nt][reg] + accA[nt][reg]);
    }
    lds_order();   // staging stores (NBA) ordered before S1N reads

    // ========== S1N: packed-S (2 chained MFMAs/nt) + per-term |x| ==========
    {
        f16x8 Bspn[4], Bs1n[4];
        #pragma unroll
        for (int nt = 0; nt < 4; ++nt) {
            Bspn[nt] = load_bh(wsf, FR_SPN + nt, lane);
            Bs1n[nt] = load_bh(wsf, FR_S1N + nt, lane);
        }
        const int m8 = m * 8;
        // packed A: k=q*8+j -> nbr (k>>2), feat (k&3): nbrs {2q,2q+1} (+8)
        union { f16x8 v; uint2 h[2]; } Ap0, Ap1;
        Ap0.h[0] = *(const uint2*)(NBA + (2 * q) * NBA_STR + m8);
        Ap0.h[1] = *(const uint2*)(NBA + (2 * q + 1) * NBA_STR + m8);
        Ap1.h[0] = *(const uint2*)(NBA + (2 * q + 8) * NBA_STR + m8);
        Ap1.h[1] = *(const uint2*)(NBA + (2 * q + 9) * NBA_STR + m8);

        f32x4 accS[4], accA[4];
        #pragma unroll
        for (int nt = 0; nt < 4; ++nt) {
            accS[nt] = mfma1(Ap1.v, Bspn[nt],
                       mfma1(Ap0.v, Bspn[nt], cinit(BSN[nt * 16 + c])));
            accA[nt] = cinit(0.f);
        }
        union { f16x8 v; unsigned u[4]; uint2 h[2]; } A;
        A.u[2] = H16_ONE; A.u[3] = 0;        // k=4 bias slot
        #pragma unroll
        for (int mm = 0; mm < 16; ++mm) {
            A.h[0] = *(const uint2*)(NBA + mm * NBA_STR + m8);
            #pragma unroll
            for (int nt = 0; nt < 4; ++nt) {
                f32x4 cc = mfma1(A.v, Bs1n[nt], ZC);
                #pragma unroll
                for (int reg = 0; reg < 4; ++reg)
                    accA[nt][reg] += fabsf(cc[reg]);
            }
        }
        lds_order();   // NBA reads done; BIG stores below alias it
        #pragma unroll
        for (int nt = 0; nt < 4; ++nt)
            #pragma unroll
            for (int reg = 0; reg < 4; ++reg)
                *(_Float16*)(BIG + (q * 4 + reg) * BIG_STR + (nt * 16 + c) * 2)
                    = (_Float16)(accS[nt][reg] + accA[nt][reg]);
    }
    lds_order();

    // ========== FN + FO merged (independent streams, one region) ===========
    {
        f16x8 An0 = lds_af(BIG,  BIG_STR, 0, lane);
        f16x8 An1 = lds_af(BIG,  BIG_STR, 64, lane);
        f16x8 Ao0 = lds_af(BIG2, BIG_STR, 0, lane);
        f16x8 Ao1 = lds_af(BIG2, BIG_STR, 64, lane);
        #pragma unroll
        for (int nt = 0; nt < 4; ++nt) {
            f16x8 Bn0 = load_bh(wsf, FR_FN + nt, lane);
            f16x8 Bn1 = load_bh(wsf, FR_FN + 4 + nt, lane);
            f32x4 cn = mfma1(An0, Bn0, cinit(BFN[nt * 16 + c]));
            cn = mfma1(An1, Bn1, cn);
            f16x8 Bo0 = load_bh(wsf, FR_FO + nt, lane);
            f16x8 Bo1 = load_bh(wsf, FR_FO + 4 + nt, lane);
            f32x4 co = mfma1(Ao0, Bo0, cinit(BFO[nt * 16 + c]));
            co = mfma1(Ao1, Bo1, co);
            #pragma unroll
            for (int reg = 0; reg < 4; ++reg) {
                *(_Float16*)(BIG + (q * 4 + reg) * BIG_STR + (nt * 16 + c) * 2)
                    = (_Float16)fmaxf(cn[reg], 0.f);
                *(_Float16*)(BIG2 + (q * 4 + reg) * BIG_STR + (nt * 16 + c) * 2)
                    = (_Float16)fmaxf(co[reg], 0.f);
            }
        }
    }
    lds_order();

    // ========== PSI: h3 = relu(g@WG + z_n@ZN + z_o@ZO) (bias in WG k=4) ====
    {
        f16x8 An0 = lds_af(BIG,  BIG_STR, 0, lane);
        f16x8 An1 = lds_af(BIG,  BIG_STR, 64, lane);
        f16x8 Ao0 = lds_af(BIG2, BIG_STR, 0, lane);
        f16x8 Ao1 = lds_af(BIG2, BIG_STR, 64, lane);
        #pragma unroll
        for (int nt = 0; nt < 4; ++nt) {
            f16x8 Bg  = load_bh(wsf, FR_WG + nt, lane);
            f16x8 Bn0 = load_bh(wsf, FR_ZN + nt, lane);
            f16x8 Bn1 = load_bh(wsf, FR_ZN + 4 + nt, lane);
            f16x8 Bo0 = load_bh(wsf, FR_ZO + nt, lane);
            f16x8 Bo1 = load_bh(wsf, FR_ZO + 4 + nt, lane);
            f32x4 cc = mfma1(gA.v, Bg, ZC);
            cc = mfma1(An0, Bn0, cc);
            cc = mfma1(An1, Bn1, cc);
            cc = mfma1(Ao0, Bo0, cc);
            cc = mfma1(Ao1, Bo1, cc);
            #pragma unroll
            for (int reg = 0; reg < 4; ++reg)
                *(_Float16*)(BIG + (q * 4 + reg) * BIG_STR + (nt * 16 + c) * 2)
                    = (_Float16)fmaxf(cc[reg], 0.f);
        }
    }
    lds_order();

    // ========== PSI2 -> OUT ================================================
    {
        float b_p2 = (c < 2) ? bpsi2[c] : 0.f;
        f16x8 Bp20 = load_bh(wsf, FR_PSI2 + 0, lane);
        f16x8 Bp21 = load_bh(wsf, FR_PSI2 + 1, lane);
        f16x8 A0 = lds_af(BIG, BIG_STR, 0, lane);
        f16x8 A1 = lds_af(BIG, BIG_STR, 64, lane);
        f32x4 ca = mfma1(A0, Bp20, cinit(b_p2));
        f32x4 cb = mfma1(A1, Bp21, ZC);
        if (c < 2) {
            #pragma unroll
            for (int reg = 0; reg < 4; ++reg)
                *(float*)(OUTA + (q * 4 + reg) * 8 + c * 4) = ca[reg] + cb[reg];
        }
    }
    lds_order();

    // epilogue
    if (lane < 16) {
        float2 a  = *(const float2*)(OUTA + lane * 8);
        float2 bb = *(const float2*)(BAR + lane * 8);
        float a0 = two_tanh(a.x) + bb.x;
        float a1 = two_tanh(a.y) + bb.y;
        float amax = fmaxf(fabsf(a0), fabsf(a1));
        float inv_alpha = fmaxf(amax * 0.5f, 1.0f);
        float rr = fast_rcp(inv_alpha);
        float2 o; o.x = a0 * rr; o.y = a1 * rr;
        *(float2*)(out + (size_t)(row0 + lane) * 2) = o;
    }
}

extern "C" void kernel_launch(void* const* d_in, const int* in_sizes, int n_in,
                              void* d_out, int out_size, void* d_ws, size_t ws_size,
                              hipStream_t stream) {
    const float* x     = (const float*)d_in[0];
    const float* Wp1n  = (const float*)d_in[1];
    const float* bp1n  = (const float*)d_in[2];
    const float* Wp2n  = (const float*)d_in[3];
    const float* bp2n  = (const float*)d_in[4];
    const float* Wr1n  = (const float*)d_in[5];
    const float* br1n  = (const float*)d_in[6];
    const float* Wr2n  = (const float*)d_in[7];
    const float* br2n  = (const float*)d_in[8];
    const float* Wp1o  = (const float*)d_in[9];
    const float* bp1o  = (const float*)d_in[10];
    const float* Wp2o  = (const float*)d_in[11];
    const float* bp2o  = (const float*)d_in[12];
    const float* Wr1o  = (const float*)d_in[13];
    const float* br1o  = (const float*)d_in[14];
    const float* Wr2o  = (const float*)d_in[15];
    const float* br2o  = (const float*)d_in[16];
    const float* Wpsi1 = (const float*)d_in[17];
    const float* bpsi1 = (const float*)d_in[18];
    const float* Wpsi2 = (const float*)d_in[19];
    const float* bpsi2 = (const float*)d_in[20];
    float* out = (float*)d_out;

    int nb = in_sizes[0] / XW;               // 131072
    _Float16* wsf = (_Float16*)d_ws;         // ~56 KB frag+bias table

    bn_prep<<<N_FRAGS + 4, 64, 0, stream>>>(Wp1n, Wp2n, Wr1n, Wr2n,
                                            Wp1o, Wp2o, Wr1o, Wr2o,
                                            Wpsi1, Wpsi2,
                                            bp1n, bp1o, bp2n, bp2o,
                                            br1n, br1o, br2n, br2o,
                                            bpsi1, wsf);

    int groups = (nb + 15) / 16;             // 8192
    int blocks = (groups + 3) / 4;           // 2048 (4 groups per block)
    bn_main<<<blocks, 256, 0, stream>>>(x, wsf, bpsi2, out, nb);
}